// Round 11
// baseline (512.457 us; speedup 1.0000x reference)
//
#include <hip/hip_runtime.h>

// SGC layer: N=100000 nodes, E=1600000 edges, D_IN=32, D_OUT=64, 2 hops,
// per-hop cut of the 160000 lowest-cosine edges (exact top-k w/ index ties).

constexpr int NN   = 100000;
constexpr int NE   = 1600000;
constexpr int DI   = 32;
constexpr int DO   = 64;
constexpr int KCUT = 160000;
constexpr int NB   = 98;      // buckets of 1024 node-ids
constexpr int CH   = 4096;    // edges per bin chunk
constexpr int HB   = 256;     // blocks for the big histogram
constexpr int HBH  = 512;     // blocks for bucket histogram
constexpr int SCAP = 19456;   // LDS staging capacity (edges/bucket)

typedef unsigned long long u64;

// ---------------- binned CSR build ----------------
// packed edge: bits 38-47 dloc (dst & 1023), 21-37 src, 0-20 eid

// per-block partial histograms: no pre-zero, no global atomics
__global__ void k_bhist(const int* __restrict__ dst, unsigned* __restrict__ bpart) {
  __shared__ unsigned lh[128];
  int t = threadIdx.x;
  if (t < 128) lh[t] = 0u;
  __syncthreads();
  int stride = gridDim.x * blockDim.x;
  for (int e = blockIdx.x * blockDim.x + t; e < NE; e += stride)
    atomicAdd(&lh[((unsigned)dst[e]) >> 10], 1u);
  __syncthreads();
  if (t < 128) bpart[blockIdx.x * 128 + t] = lh[t];
}

// column-reduce partials + scan -> bstart/bcur (one block, 128 threads)
__global__ void k_bscan2(const unsigned* __restrict__ bpart, unsigned* __restrict__ bstart,
                         unsigned* __restrict__ bcur) {
  __shared__ unsigned s[128];
  int t = threadIdx.x;
  unsigned sum = 0;
  for (int b = 0; b < HBH; b++) sum += bpart[b * 128 + t];
  s[t] = sum; __syncthreads();
  for (int off = 1; off < 128; off <<= 1) {
    unsigned x = (t >= off) ? s[t - off] : 0u;
    __syncthreads();
    s[t] += x;
    __syncthreads();
  }
  unsigned incl = s[t], excl = incl - sum;
  if (t < NB) { bstart[t] = excl; bcur[t] = excl; }
  if (t == NB - 1) bstart[NB] = incl;   // == NE
}

// block-aggregated multisplit: one global atomic per (bucket, chunk)
__global__ void k_bin(const int* __restrict__ src, const int* __restrict__ dst,
                      unsigned* __restrict__ bcur, u64* __restrict__ binned) {
  __shared__ unsigned h1[128], h2[128], res[128];
  int t = threadIdx.x;
  for (int base = blockIdx.x * CH; base < NE; base += gridDim.x * CH) {
    int nE = min(CH, NE - base);
    if (t < 128) h1[t] = 0u;
    __syncthreads();
    for (int i = t; i < nE; i += 256)
      atomicAdd(&h1[((unsigned)dst[base + i]) >> 10], 1u);
    __syncthreads();
    if (t < 128) { unsigned c = h1[t]; res[t] = c ? atomicAdd(&bcur[t], c) : 0u; h2[t] = 0u; }
    __syncthreads();
    for (int i = t; i < nE; i += 256) {   // chunk re-read hits L1/L2
      unsigned d = (unsigned)dst[base + i];
      unsigned bb = d >> 10;
      u64 pk = ((u64)(d & 1023u) << 38) | ((u64)(unsigned)src[base + i] << 21)
             | (u64)(unsigned)(base + i);
      unsigned r = atomicAdd(&h2[bb], 1u);
      binned[res[bb] + r] = pk;
    }
    __syncthreads();
  }
}

// per-bucket degree count in LDS -> coalesced degi write
__global__ void k_bucket_deg(const u64* __restrict__ binned, const unsigned* __restrict__ bstart,
                             unsigned* __restrict__ degi) {
  __shared__ unsigned cnt[1024];
  int t = threadIdx.x;
  int b = blockIdx.x;
  for (int i = t; i < 1024; i += 256) cnt[i] = 0u;
  __syncthreads();
  unsigned j0 = bstart[b], j1 = bstart[b + 1];
  for (unsigned j = j0 + t; j < j1; j += 256)
    atomicAdd(&cnt[(unsigned)(binned[j] >> 38)], 1u);
  __syncthreads();
  int base = b << 10;
  for (int i = t; i < 1024; i += 256)
    if (base + i < NN) degi[base + i] = cnt[i];
}

// LDS-staged bucket scatter: scatter lands in LDS, global write is one
// coalesced streaming copy.
__global__ void k_bucket_scatter(const u64* __restrict__ binned, const unsigned* __restrict__ bstart,
                                 const unsigned* __restrict__ rowptr, uint2* __restrict__ csr) {
  extern __shared__ unsigned smem[];
  unsigned* curl = smem;                    // 1024 cursors (local offsets)
  u64* stage = (u64*)(smem + 1024);         // SCAP entries
  int t = threadIdx.x;
  int b = blockIdx.x;
  unsigned j0 = bstart[b], j1 = bstart[b + 1];
  int base = b << 10;
  for (int i = t; i < 1024; i += 256)
    curl[i] = (base + i < NN) ? (rowptr[base + i] - j0) : 0u;
  __syncthreads();
  for (unsigned j = j0 + t; j < j1; j += 256) {
    u64 pk = binned[j];
    unsigned dloc = (unsigned)(pk >> 38);
    unsigned s = (unsigned)((pk >> 21) & 0x1FFFFu);
    unsigned e = (unsigned)(pk & 0x1FFFFFu);
    unsigned p = atomicAdd(&curl[dloc], 1u);
    u64 entry = ((u64)e << 32) | (u64)s;    // uint2{x=src, y=eid}
    if (p < (unsigned)SCAP) stage[p] = entry;
    else csr[j0 + p] = make_uint2(s, e);    // statistical-overflow fallback
  }
  __syncthreads();
  unsigned cnt = j1 - j0;
  u64* gout = (u64*)(csr + j0);
  for (unsigned i = t; i < cnt; i += 256)
    if (i < (unsigned)SCAP) gout[i] = stage[i];
}

// ---------------- prefix sum (rowptr) ----------------

__global__ void k_psum_a(const unsigned* __restrict__ degi, unsigned* __restrict__ bsum) {
  __shared__ unsigned s[1024];
  int t = threadIdx.x;
  int i = blockIdx.x * 1024 + t;
  s[t] = (i < NN) ? degi[i] : 0u;
  __syncthreads();
  for (int off = 512; off > 0; off >>= 1) {
    if (t < off) s[t] += s[t + off];
    __syncthreads();
  }
  if (t == 0) bsum[blockIdx.x] = s[0];
}

__global__ void k_psum_b(unsigned* bsum, int nb, unsigned* rowptr) {
  if (threadIdx.x == 0 && blockIdx.x == 0) {
    unsigned run = 0;
    for (int b = 0; b < nb; b++) { unsigned v = bsum[b]; bsum[b] = run; run += v; }
    rowptr[NN] = run;   // == NE
  }
}

// also emits nrm (fused old k_norm)
__global__ void k_psum_c(const unsigned* __restrict__ degi, const unsigned* __restrict__ bsum,
                         unsigned* __restrict__ rowptr, float* __restrict__ nrm) {
  __shared__ unsigned s[1024];
  int t = threadIdx.x;
  int i = blockIdx.x * 1024 + t;
  unsigned v = (i < NN) ? degi[i] : 0u;
  s[t] = v; __syncthreads();
  for (int off = 1; off < 1024; off <<= 1) {
    unsigned x = (t >= off) ? s[t - off] : 0u;
    __syncthreads();
    s[t] += x;
    __syncthreads();
  }
  if (i < NN) {
    rowptr[i] = bsum[blockIdx.x] + s[t] - v;
    unsigned d = v < 1u ? 1u : v;
    nrm[i] = (float)(1.0 / sqrt((double)d));   // == pow(deg, -0.5)
  }
}

// ---------------- per-hop kernels ----------------

// 8 nodes per 256-thread block; lane = feature dim
__global__ void k_rownorm(const float* __restrict__ h, const float* __restrict__ nrm,
                          float* __restrict__ nh, float* __restrict__ hn) {
  int lane = threadIdx.x & 31;
  int n = blockIdx.x * 8 + (threadIdx.x >> 5);
  float v = h[n * DI + lane];
  double sq = (double)v * (double)v;
  #pragma unroll
  for (int m = 16; m > 0; m >>= 1) sq += __shfl_xor(sq, m, 32);
  double den = sqrt(sq);
  if (den < 1e-12) den = 1e-12;
  nh[n * DI + lane] = (float)((double)v / den);
  hn[n * DI + lane] = v * nrm[n];
}

// cosine, MLP-restructured, PURE: 32-lane group per node = 8 edge slots x 4
// dim slices; 16 independent float4 gathers in flight per group.
__global__ void k_cos(const unsigned* __restrict__ rowptr, const uint2* __restrict__ csr,
                      const float* __restrict__ nh, u64* __restrict__ key) {
  int t = threadIdx.x;
  int lane = t & 31;
  int sl = lane >> 2;        // edge slot 0..7
  int ds = lane & 3;         // dim slice 0..3 (8 dims each)
  int n = blockIdx.x * 8 + (t >> 5);
  const float4* drow = (const float4*)(nh + (size_t)n * DI + ds * 8);
  float4 d0 = drow[0], d1 = drow[1];
  unsigned j0 = rowptr[n], j1 = rowptr[n + 1];
  for (unsigned base = j0; base < j1; base += 8) {
    unsigned j = base + sl;
    bool val = (j < j1);
    uint2 c = val ? csr[j] : make_uint2(0u, 0u);
    const float4* arow = (const float4*)(nh + (size_t)c.x * DI + ds * 8);
    float4 a0 = arow[0], a1 = arow[1];   // two independent gathers
    double p = (double)a0.x * d0.x + (double)a0.y * d0.y
             + (double)a0.z * d0.z + (double)a0.w * d0.w
             + (double)a1.x * d1.x + (double)a1.y * d1.y
             + (double)a1.z * d1.z + (double)a1.w * d1.w;
    p += __shfl_xor(p, 1, 32);
    p += __shfl_xor(p, 2, 32);
    if (val && ds == 0) {
      float cf = (float)p;
      unsigned u = __float_as_uint(cf);
      u = (u & 0x80000000u) ? ~u : (u | 0x80000000u);   // monotone float->uint
      key[j] = ((u64)u << 32) | (u64)c.y;
    }
  }
}

// ---------------- radix select (K-th smallest 64-bit key) ----------------
// state[0] = prefix (becomes the K-th smallest key), state[1] = k remaining
// cur[0] = candidate count, cur[2] = reduce-done counter

// big histogram, atomic-free merge; block 0 re-inits radix state
__global__ void k_hist_big(const u64* __restrict__ keys, unsigned* __restrict__ ghist,
                           u64* state, unsigned* cur) {
  __shared__ unsigned lh[4096];
  int t = threadIdx.x;
  if (blockIdx.x == 0 && t == 0) {
    state[0] = 0ull; state[1] = (u64)KCUT; cur[0] = 0u; cur[1] = 0u; cur[2] = 0u;
  }
  for (int i = t; i < 4096; i += 256) lh[i] = 0u;
  __syncthreads();
  int stride = gridDim.x * blockDim.x;
  for (int j = blockIdx.x * blockDim.x + t; j < NE; j += stride)
    atomicAdd(&lh[(unsigned)(keys[j] >> 52)], 1u);
  __syncthreads();
  unsigned* gh = ghist + (size_t)blockIdx.x * 4096;
  for (int i = t; i < 4096; i += 256) gh[i] = lh[i];
}

// column-sum ghist -> hist; LAST block also performs the 12-bit select at
// shift 52 (threadfence + done-counter pattern). 16 blocks x 256 threads.
__global__ void k_hist_reduce_sel(const unsigned* __restrict__ ghist, unsigned* __restrict__ hist,
                                  u64* state, unsigned* cur) {
  __shared__ unsigned ssum[256];
  __shared__ unsigned isLast;
  int t = threadIdx.x;
  int bin = blockIdx.x * 256 + t;
  unsigned s = 0;
  for (int b = 0; b < HB; b++) s += ghist[(size_t)b * 4096 + bin];
  hist[bin] = s;
  __threadfence();
  if (t == 0) isLast = (atomicAdd(&cur[2], 1u) == gridDim.x - 1u) ? 1u : 0u;
  __syncthreads();
  if (!isLast) return;
  __threadfence();
  // select: 256 threads x 16 bins each
  unsigned loc[16]; unsigned tot = 0;
  #pragma unroll
  for (int i = 0; i < 16; i++) { loc[i] = hist[t * 16 + i]; tot += loc[i]; }
  unsigned krem = (unsigned)state[1];
  ssum[t] = tot; __syncthreads();
  for (int off = 1; off < 256; off <<= 1) {
    unsigned x = (t >= off) ? ssum[t - off] : 0u;
    __syncthreads();
    ssum[t] += x;
    __syncthreads();
  }
  unsigned incl = ssum[t], excl = incl - tot;
  if (incl >= krem && excl < krem) {
    unsigned run = excl;
    #pragma unroll
    for (int i = 0; i < 16; i++) {
      if (krem <= run + loc[i]) {
        state[0] |= ((u64)(t * 16 + i)) << 52;
        state[1] = (u64)(krem - run);
        break;
      }
      run += loc[i];
    }
  }
}

// block-aggregated compaction: LDS staging + one global atomic per flush
__global__ void k_compact(const u64* __restrict__ keys, const u64* __restrict__ state,
                          u64* __restrict__ outbuf, unsigned* __restrict__ cursor) {
  __shared__ u64 buf[768];
  __shared__ unsigned cnt, gbase;
  int t = threadIdx.x;
  if (t == 0) cnt = 0u;
  __syncthreads();
  u64 pref = state[0];
  int stride = gridDim.x * blockDim.x;
  for (int j0 = blockIdx.x * blockDim.x; j0 < NE; j0 += stride) {
    int j = j0 + t;
    if (j < NE) {
      u64 k = keys[j];
      if (((k ^ pref) >> 52) == 0ull) {
        unsigned pos = atomicAdd(&cnt, 1u);
        buf[pos] = k;
      }
    }
    __syncthreads();
    if (cnt >= 512u) {
      if (t == 0) gbase = atomicAdd(cursor, cnt);
      __syncthreads();
      for (unsigned i = t; i < cnt; i += blockDim.x) outbuf[gbase + i] = buf[i];
      __syncthreads();
      if (t == 0) cnt = 0u;
      __syncthreads();
    }
  }
  if (t == 0 && cnt > 0u) gbase = atomicAdd(cursor, cnt);
  __syncthreads();
  for (unsigned i = t; i < cnt; i += blockDim.x) outbuf[gbase + i] = buf[i];
}

// resolve the remaining 52 bits on the candidate set in one block:
// 4 x 12-bit digit rounds + 1 x 4-bit round over ~25K L2-hot candidates.
__global__ void __launch_bounds__(1024) k_finish2(const u64* __restrict__ cb,
                                                  const unsigned* __restrict__ cur,
                                                  u64* __restrict__ state) {
  __shared__ unsigned lh[4096];
  __shared__ unsigned ssum[1024];
  __shared__ u64 spref;
  __shared__ unsigned skrem;
  int t = threadIdx.x;
  unsigned cnt = cur[0];
  if (t == 0) { spref = state[0]; skrem = (unsigned)state[1]; }
  __syncthreads();
  for (int r = 0; r < 5; r++) {
    int shift = (r < 4) ? (40 - 12 * r) : 0;
    int width = (r < 4) ? 12 : 4;
    int nbins = 1 << width;
    int check = shift + width;
    for (int i = t; i < nbins; i += 1024) lh[i] = 0u;
    __syncthreads();
    u64 pref = spref;
    for (unsigned j = t; j < cnt; j += 1024) {
      u64 k = cb[j];
      if (((k ^ pref) >> check) == 0ull)
        atomicAdd(&lh[(unsigned)((k >> shift) & (u64)(nbins - 1))], 1u);
    }
    __syncthreads();
    int per = (nbins + 1023) / 1024;        // 4 or 1
    unsigned loc[4]; unsigned tot = 0;
    for (int i = 0; i < per; i++) {
      int b = t * per + i;
      loc[i] = (b < nbins) ? lh[b] : 0u;
      tot += loc[i];
    }
    ssum[t] = tot; __syncthreads();
    for (int off = 1; off < 1024; off <<= 1) {
      unsigned x = (t >= off) ? ssum[t - off] : 0u;
      __syncthreads();
      ssum[t] += x;
      __syncthreads();
    }
    unsigned incl = ssum[t], excl = incl - tot;
    unsigned krem = skrem;
    __syncthreads();
    if (incl >= krem && excl < krem) {
      unsigned run = excl;
      for (int i = 0; i < per; i++) {
        if (krem <= run + loc[i]) {
          spref |= ((u64)(t * per + i)) << shift;
          skrem = krem - run;
          break;
        }
        run += loc[i];
      }
    }
    __syncthreads();
  }
  if (t == 0) state[0] = spref;   // exact K-th smallest key
}

// ---------------- propagate, MLP-restructured like k_cos ----------------

__global__ void k_prop(const unsigned* __restrict__ rowptr, const uint2* __restrict__ csr,
                       const u64* __restrict__ key, const u64* __restrict__ state,
                       const float* __restrict__ hn, const float* __restrict__ nrm,
                       float* __restrict__ hout) {
  int t = threadIdx.x;
  int lane = t & 31;
  int sl = lane >> 2, ds = lane & 3;
  int n = blockIdx.x * 8 + (t >> 5);
  u64 X = state[0];                         // cut iff key <= X
  unsigned j0 = rowptr[n], j1 = rowptr[n + 1];
  double acc[8];
  #pragma unroll
  for (int i = 0; i < 8; i++) acc[i] = 0.0;
  for (unsigned base = j0; base < j1; base += 8) {
    unsigned j = base + sl;
    bool val = (j < j1);
    uint2 c = val ? csr[j] : make_uint2(0u, 0u);
    u64 k = val ? key[j] : 0ull;
    bool keep = val && (k > X);
    const float4* arow = (const float4*)(hn + (size_t)c.x * DI + ds * 8);
    float4 a0 = arow[0], a1 = arow[1];      // two independent gathers
    if (keep) {
      acc[0] += (double)a0.x; acc[1] += (double)a0.y;
      acc[2] += (double)a0.z; acc[3] += (double)a0.w;
      acc[4] += (double)a1.x; acc[5] += (double)a1.y;
      acc[6] += (double)a1.z; acc[7] += (double)a1.w;
    }
  }
  #pragma unroll
  for (int m = 4; m <= 16; m <<= 1) {
    #pragma unroll
    for (int i = 0; i < 8; i++) acc[i] += __shfl_xor(acc[i], m, 32);
  }
  if (sl == 0) {                            // lanes 0..3 hold dims ds*8..ds*8+7
    float nv = nrm[n];
    float4 o0, o1;
    o0.x = (float)acc[0] * nv; o0.y = (float)acc[1] * nv;
    o0.z = (float)acc[2] * nv; o0.w = (float)acc[3] * nv;
    o1.x = (float)acc[4] * nv; o1.y = (float)acc[5] * nv;
    o1.z = (float)acc[6] * nv; o1.w = (float)acc[7] * nv;
    float4* orow = (float4*)(hout + (size_t)n * DI + ds * 8);
    orow[0] = o0; orow[1] = o1;
  }
}

// ---------------- final FC: out = h @ W^T ----------------

__global__ void k_fc(const float* __restrict__ h, const float* __restrict__ W,
                     float* __restrict__ out) {
  __shared__ float Wt[DI * 65];   // Wt[d][o], padded stride 65
  __shared__ float hs[4 * DI];
  int t = threadIdx.x;
  #pragma unroll
  for (int i = 0; i < 8; i++) {
    int idx = t + i * 256;                 // idx = o*32 + d
    Wt[(idx & 31) * 65 + (idx >> 5)] = W[idx];
  }
  int n0 = blockIdx.x * 4;
  if (t < 128) hs[t] = h[n0 * DI + t];
  __syncthreads();
  int o = t & 63, nl = t >> 6;
  float acc = 0.f;
  #pragma unroll
  for (int d = 0; d < DI; d++) acc += hs[nl * DI + d] * Wt[d * 65 + o];
  out[(n0 + nl) * DO + o] = acc;
}

// ---------------- launch ----------------

extern "C" void kernel_launch(void* const* d_in, const int* in_sizes, int n_in,
                              void* d_out, int out_size, void* d_ws, size_t ws_size,
                              hipStream_t stream) {
  const float* feat = (const float*)d_in[0];
  const int*   src  = (const int*)d_in[1];
  const int*   dst  = (const int*)d_in[2];
  const float* W    = (const float*)d_in[3];
  float*       out  = (float*)d_out;

  // workspace layout (~80 MB), all u64 pointers 8B-aligned
  float* bufA = (float*)d_ws;                       // NN*DI f32
  float* bufB = bufA + (size_t)NN * DI;
  float* bufC = bufB + (size_t)NN * DI;
  u64*   key  = (u64*)(bufC + (size_t)NN * DI);     // NE u64
  u64*   cbuf2 = key + NE;                          // NE u64 (aliased: binned, ghist)
  u64*   binned = cbuf2;                            // dead before cbuf1 is used
  unsigned* ghist = (unsigned*)cbuf2;               // HB*4096 u32 = 4MB
  float*    nrm     = (float*)(cbuf2 + NE);
  unsigned* degi    = (unsigned*)(nrm + NN);
  unsigned* rowptr  = degi + NN;                    // NN+2 (pad keeps 8B alignment)
  unsigned* fill    = rowptr + NN + 2;              // (unused, layout stability)
  unsigned* bsum    = fill + NN;                    // 128
  unsigned* hist    = bsum + 128;                   // 4096
  unsigned* cur     = hist + 4096;                  // 4: cnt1, spare, done, pad
  u64*      state   = (u64*)(cur + 4);              // 2
  uint2*    csr     = (uint2*)(state + 2);          // NE uint2
  unsigned* bstart  = (unsigned*)(csr + NE);        // NB+1 (pad to 100)
  unsigned* bcur    = bstart + 100;                 // 128
  unsigned* bpart   = bcur + 128;                   // HBH*128 = 256KB

  // ---- binned CSR build (edges are hop-invariant) ----
  k_bhist<<<HBH, 256, 0, stream>>>(dst, bpart);
  k_bscan2<<<1, 128, 0, stream>>>(bpart, bstart, bcur);
  k_bin<<<(NE + CH - 1) / CH, 256, 0, stream>>>(src, dst, bcur, binned);
  k_bucket_deg<<<NB, 256, 0, stream>>>(binned, bstart, degi);
  int nb = (NN + 1023) / 1024;   // 98
  k_psum_a<<<nb, 1024, 0, stream>>>(degi, bsum);
  k_psum_b<<<1, 1, 0, stream>>>(bsum, nb, rowptr);
  k_psum_c<<<nb, 1024, 0, stream>>>(degi, bsum, rowptr, nrm);
  size_t scatter_lds = 1024 * sizeof(unsigned) + (size_t)SCAP * sizeof(u64);  // ~156KB
  k_bucket_scatter<<<NB, 256, scatter_lds, stream>>>(binned, bstart, rowptr, csr);

  // hop 0: nh=A, hn=B, out=A, cbuf1=C   |   hop 1: nh=C, hn=B, out=C, cbuf1=A
  const float* hin = feat;
  for (int hop = 0; hop < 2; hop++) {
    float* nh = (hop == 0) ? bufA : bufC;
    float* hn = bufB;
    float* ho = (hop == 0) ? bufA : bufC;
    u64* cbuf1 = (u64*)((hop == 0) ? bufC : bufA);  // free this hop

    k_rownorm<<<NN / 8, 256, 0, stream>>>(hin, nrm, nh, hn);
    k_cos<<<NN / 8, 256, 0, stream>>>(rowptr, csr, nh, key);

    k_hist_big<<<HB, 256, 0, stream>>>(key, ghist, state, cur);      // + init
    k_hist_reduce_sel<<<16, 256, 0, stream>>>(ghist, hist, state, cur);
    k_compact<<<512, 256, 0, stream>>>(key, state, cbuf1, cur + 0);
    k_finish2<<<1, 1024, 0, stream>>>(cbuf1, cur, state);

    k_prop<<<NN / 8, 256, 0, stream>>>(rowptr, csr, key, state, hn, nrm, ho);
    hin = ho;
  }
  k_fc<<<NN / 4, 256, 0, stream>>>(hin, W, out);
}

// Round 12
// 481.614 us; speedup vs baseline: 1.0640x; 1.0640x over previous
//
#include <hip/hip_runtime.h>

// SGC layer: N=100000 nodes, E=1600000 edges, D_IN=32, D_OUT=64, 2 hops,
// per-hop cut of the 160000 lowest-cosine edges (exact top-k w/ index ties).

constexpr int NN   = 100000;
constexpr int NE   = 1600000;
constexpr int DI   = 32;
constexpr int DO   = 64;
constexpr int KCUT = 160000;
constexpr int NB   = 98;      // buckets of 1024 node-ids
constexpr int CH   = 4096;    // edges per bin chunk
constexpr int HB   = 256;     // blocks for the big histogram
constexpr int HBH  = 512;     // blocks for bucket histogram
constexpr int SCAP = 19456;   // LDS staging capacity (edges/bucket)
constexpr int FCAP = 6144;    // finish2 LDS candidate capacity

typedef unsigned long long u64;

// ---------------- binned CSR build ----------------
// packed edge: bits 38-47 dloc (dst & 1023), 21-37 src, 0-20 eid

// per-block partial histograms: no pre-zero, no global atomics
__global__ void k_bhist(const int* __restrict__ dst, unsigned* __restrict__ bpart) {
  __shared__ unsigned lh[128];
  int t = threadIdx.x;
  if (t < 128) lh[t] = 0u;
  __syncthreads();
  int stride = gridDim.x * blockDim.x;
  for (int e = blockIdx.x * blockDim.x + t; e < NE; e += stride)
    atomicAdd(&lh[((unsigned)dst[e]) >> 10], 1u);
  __syncthreads();
  if (t < 128) bpart[blockIdx.x * 128 + t] = lh[t];
}

// column-reduce partials + scan -> bstart/bcur (one block, 128 threads)
__global__ void k_bscan2(const unsigned* __restrict__ bpart, unsigned* __restrict__ bstart,
                         unsigned* __restrict__ bcur) {
  __shared__ unsigned s[128];
  int t = threadIdx.x;
  unsigned sum = 0;
  for (int b = 0; b < HBH; b++) sum += bpart[b * 128 + t];
  s[t] = sum; __syncthreads();
  for (int off = 1; off < 128; off <<= 1) {
    unsigned x = (t >= off) ? s[t - off] : 0u;
    __syncthreads();
    s[t] += x;
    __syncthreads();
  }
  unsigned incl = s[t], excl = incl - sum;
  if (t < NB) { bstart[t] = excl; bcur[t] = excl; }
  if (t == NB - 1) bstart[NB] = incl;   // == NE
}

// block-aggregated multisplit: one global atomic per (bucket, chunk)
__global__ void k_bin(const int* __restrict__ src, const int* __restrict__ dst,
                      unsigned* __restrict__ bcur, u64* __restrict__ binned) {
  __shared__ unsigned h1[128], h2[128], res[128];
  int t = threadIdx.x;
  for (int base = blockIdx.x * CH; base < NE; base += gridDim.x * CH) {
    int nE = min(CH, NE - base);
    if (t < 128) h1[t] = 0u;
    __syncthreads();
    for (int i = t; i < nE; i += 256)
      atomicAdd(&h1[((unsigned)dst[base + i]) >> 10], 1u);
    __syncthreads();
    if (t < 128) { unsigned c = h1[t]; res[t] = c ? atomicAdd(&bcur[t], c) : 0u; h2[t] = 0u; }
    __syncthreads();
    for (int i = t; i < nE; i += 256) {   // chunk re-read hits L1/L2
      unsigned d = (unsigned)dst[base + i];
      unsigned bb = d >> 10;
      u64 pk = ((u64)(d & 1023u) << 38) | ((u64)(unsigned)src[base + i] << 21)
             | (u64)(unsigned)(base + i);
      unsigned r = atomicAdd(&h2[bb], 1u);
      binned[res[bb] + r] = pk;
    }
    __syncthreads();
  }
}

// per-bucket degree count in LDS -> coalesced degi write
__global__ void k_bucket_deg(const u64* __restrict__ binned, const unsigned* __restrict__ bstart,
                             unsigned* __restrict__ degi) {
  __shared__ unsigned cnt[1024];
  int t = threadIdx.x;
  int b = blockIdx.x;
  for (int i = t; i < 1024; i += 256) cnt[i] = 0u;
  __syncthreads();
  unsigned j0 = bstart[b], j1 = bstart[b + 1];
  for (unsigned j = j0 + t; j < j1; j += 256)
    atomicAdd(&cnt[(unsigned)(binned[j] >> 38)], 1u);
  __syncthreads();
  int base = b << 10;
  for (int i = t; i < 1024; i += 256)
    if (base + i < NN) degi[base + i] = cnt[i];
}

// LDS-staged bucket scatter: scatter lands in LDS, global write is one
// coalesced streaming copy.
__global__ void k_bucket_scatter(const u64* __restrict__ binned, const unsigned* __restrict__ bstart,
                                 const unsigned* __restrict__ rowptr, uint2* __restrict__ csr) {
  extern __shared__ unsigned smem[];
  unsigned* curl = smem;                    // 1024 cursors (local offsets)
  u64* stage = (u64*)(smem + 1024);         // SCAP entries
  int t = threadIdx.x;
  int b = blockIdx.x;
  unsigned j0 = bstart[b], j1 = bstart[b + 1];
  int base = b << 10;
  for (int i = t; i < 1024; i += 256)
    curl[i] = (base + i < NN) ? (rowptr[base + i] - j0) : 0u;
  __syncthreads();
  for (unsigned j = j0 + t; j < j1; j += 256) {
    u64 pk = binned[j];
    unsigned dloc = (unsigned)(pk >> 38);
    unsigned s = (unsigned)((pk >> 21) & 0x1FFFFu);
    unsigned e = (unsigned)(pk & 0x1FFFFFu);
    unsigned p = atomicAdd(&curl[dloc], 1u);
    u64 entry = ((u64)e << 32) | (u64)s;    // uint2{x=src, y=eid}
    if (p < (unsigned)SCAP) stage[p] = entry;
    else csr[j0 + p] = make_uint2(s, e);    // statistical-overflow fallback
  }
  __syncthreads();
  unsigned cnt = j1 - j0;
  u64* gout = (u64*)(csr + j0);
  for (unsigned i = t; i < cnt; i += 256)
    if (i < (unsigned)SCAP) gout[i] = stage[i];
}

// ---------------- prefix sum (rowptr) ----------------

__global__ void k_psum_a(const unsigned* __restrict__ degi, unsigned* __restrict__ bsum) {
  __shared__ unsigned s[1024];
  int t = threadIdx.x;
  int i = blockIdx.x * 1024 + t;
  s[t] = (i < NN) ? degi[i] : 0u;
  __syncthreads();
  for (int off = 512; off > 0; off >>= 1) {
    if (t < off) s[t] += s[t + off];
    __syncthreads();
  }
  if (t == 0) bsum[blockIdx.x] = s[0];
}

__global__ void k_psum_b(unsigned* bsum, int nb, unsigned* rowptr) {
  if (threadIdx.x == 0 && blockIdx.x == 0) {
    unsigned run = 0;
    for (int b = 0; b < nb; b++) { unsigned v = bsum[b]; bsum[b] = run; run += v; }
    rowptr[NN] = run;   // == NE
  }
}

// also emits nrm (fused old k_norm)
__global__ void k_psum_c(const unsigned* __restrict__ degi, const unsigned* __restrict__ bsum,
                         unsigned* __restrict__ rowptr, float* __restrict__ nrm) {
  __shared__ unsigned s[1024];
  int t = threadIdx.x;
  int i = blockIdx.x * 1024 + t;
  unsigned v = (i < NN) ? degi[i] : 0u;
  s[t] = v; __syncthreads();
  for (int off = 1; off < 1024; off <<= 1) {
    unsigned x = (t >= off) ? s[t - off] : 0u;
    __syncthreads();
    s[t] += x;
    __syncthreads();
  }
  if (i < NN) {
    rowptr[i] = bsum[blockIdx.x] + s[t] - v;
    unsigned d = v < 1u ? 1u : v;
    nrm[i] = (float)(1.0 / sqrt((double)d));   // == pow(deg, -0.5)
  }
}

// ---------------- per-hop kernels ----------------

// 8 nodes per 256-thread block; lane = feature dim
__global__ void k_rownorm(const float* __restrict__ h, const float* __restrict__ nrm,
                          float* __restrict__ nh, float* __restrict__ hn) {
  int lane = threadIdx.x & 31;
  int n = blockIdx.x * 8 + (threadIdx.x >> 5);
  float v = h[n * DI + lane];
  double sq = (double)v * (double)v;
  #pragma unroll
  for (int m = 16; m > 0; m >>= 1) sq += __shfl_xor(sq, m, 32);
  double den = sqrt(sq);
  if (den < 1e-12) den = 1e-12;
  nh[n * DI + lane] = (float)((double)v / den);
  hn[n * DI + lane] = v * nrm[n];
}

// cosine, MLP-restructured, PURE: 32-lane group per node = 8 edge slots x 4
// dim slices; 16 independent float4 gathers in flight per group.
__global__ void k_cos(const unsigned* __restrict__ rowptr, const uint2* __restrict__ csr,
                      const float* __restrict__ nh, u64* __restrict__ key) {
  int t = threadIdx.x;
  int lane = t & 31;
  int sl = lane >> 2;        // edge slot 0..7
  int ds = lane & 3;         // dim slice 0..3 (8 dims each)
  int n = blockIdx.x * 8 + (t >> 5);
  const float4* drow = (const float4*)(nh + (size_t)n * DI + ds * 8);
  float4 d0 = drow[0], d1 = drow[1];
  unsigned j0 = rowptr[n], j1 = rowptr[n + 1];
  for (unsigned base = j0; base < j1; base += 8) {
    unsigned j = base + sl;
    bool val = (j < j1);
    uint2 c = val ? csr[j] : make_uint2(0u, 0u);
    const float4* arow = (const float4*)(nh + (size_t)c.x * DI + ds * 8);
    float4 a0 = arow[0], a1 = arow[1];   // two independent gathers
    double p = (double)a0.x * d0.x + (double)a0.y * d0.y
             + (double)a0.z * d0.z + (double)a0.w * d0.w
             + (double)a1.x * d1.x + (double)a1.y * d1.y
             + (double)a1.z * d1.z + (double)a1.w * d1.w;
    p += __shfl_xor(p, 1, 32);
    p += __shfl_xor(p, 2, 32);
    if (val && ds == 0) {
      float cf = (float)p;
      unsigned u = __float_as_uint(cf);
      u = (u & 0x80000000u) ? ~u : (u | 0x80000000u);   // monotone float->uint
      key[j] = ((u64)u << 32) | (u64)c.y;
    }
  }
}

// ---------------- radix select (K-th smallest 64-bit key) ----------------
// state[0] = prefix (becomes the K-th smallest key), state[1] = k remaining
// cur[0] = candidate count, cur[2] = reduce-done counter

// big histogram, atomic-free merge; block 0 re-inits radix state
__global__ void k_hist_big(const u64* __restrict__ keys, unsigned* __restrict__ ghist,
                           u64* state, unsigned* cur) {
  __shared__ unsigned lh[4096];
  int t = threadIdx.x;
  if (blockIdx.x == 0 && t == 0) {
    state[0] = 0ull; state[1] = (u64)KCUT; cur[0] = 0u; cur[1] = 0u; cur[2] = 0u;
  }
  for (int i = t; i < 4096; i += 256) lh[i] = 0u;
  __syncthreads();
  int stride = gridDim.x * blockDim.x;
  for (int j = blockIdx.x * blockDim.x + t; j < NE; j += stride)
    atomicAdd(&lh[(unsigned)(keys[j] >> 52)], 1u);
  __syncthreads();
  unsigned* gh = ghist + (size_t)blockIdx.x * 4096;
  for (int i = t; i < 4096; i += 256) gh[i] = lh[i];
}

// column-sum ghist -> hist; LAST block also performs the 12-bit select at
// shift 52 (threadfence + done-counter pattern). 16 blocks x 256 threads.
__global__ void k_hist_reduce_sel(const unsigned* __restrict__ ghist, unsigned* __restrict__ hist,
                                  u64* state, unsigned* cur) {
  __shared__ unsigned ssum[256];
  __shared__ unsigned isLast;
  int t = threadIdx.x;
  int bin = blockIdx.x * 256 + t;
  unsigned s = 0;
  for (int b = 0; b < HB; b++) s += ghist[(size_t)b * 4096 + bin];
  hist[bin] = s;
  __threadfence();
  if (t == 0) isLast = (atomicAdd(&cur[2], 1u) == gridDim.x - 1u) ? 1u : 0u;
  __syncthreads();
  if (!isLast) return;
  __threadfence();
  // select: 256 threads x 16 bins each
  unsigned loc[16]; unsigned tot = 0;
  #pragma unroll
  for (int i = 0; i < 16; i++) { loc[i] = hist[t * 16 + i]; tot += loc[i]; }
  unsigned krem = (unsigned)state[1];
  ssum[t] = tot; __syncthreads();
  for (int off = 1; off < 256; off <<= 1) {
    unsigned x = (t >= off) ? ssum[t - off] : 0u;
    __syncthreads();
    ssum[t] += x;
    __syncthreads();
  }
  unsigned incl = ssum[t], excl = incl - tot;
  if (incl >= krem && excl < krem) {
    unsigned run = excl;
    #pragma unroll
    for (int i = 0; i < 16; i++) {
      if (krem <= run + loc[i]) {
        state[0] |= ((u64)(t * 16 + i)) << 52;
        state[1] = (u64)(krem - run);
        break;
      }
      run += loc[i];
    }
  }
}

// block-aggregated compaction: LDS staging + one global atomic per flush
__global__ void k_compact(const u64* __restrict__ keys, const u64* __restrict__ state,
                          u64* __restrict__ outbuf, unsigned* __restrict__ cursor) {
  __shared__ u64 buf[768];
  __shared__ unsigned cnt, gbase;
  int t = threadIdx.x;
  if (t == 0) cnt = 0u;
  __syncthreads();
  u64 pref = state[0];
  int stride = gridDim.x * blockDim.x;
  for (int j0 = blockIdx.x * blockDim.x; j0 < NE; j0 += stride) {
    int j = j0 + t;
    if (j < NE) {
      u64 k = keys[j];
      if (((k ^ pref) >> 52) == 0ull) {
        unsigned pos = atomicAdd(&cnt, 1u);
        buf[pos] = k;
      }
    }
    __syncthreads();
    if (cnt >= 512u) {
      if (t == 0) gbase = atomicAdd(cursor, cnt);
      __syncthreads();
      for (unsigned i = t; i < cnt; i += blockDim.x) outbuf[gbase + i] = buf[i];
      __syncthreads();
      if (t == 0) cnt = 0u;
      __syncthreads();
    }
  }
  if (t == 0 && cnt > 0u) gbase = atomicAdd(cursor, cnt);
  __syncthreads();
  for (unsigned i = t; i < cnt; i += blockDim.x) outbuf[gbase + i] = buf[i];
}

// resolve remaining 52 bits, single block. v2: ONLY round 0 (bits 40-51)
// streams the global candidate buffer; survivors of the 24-bit prefix are
// compacted into LDS (~tens expected, cap FCAP) and rounds 1-4 run on LDS.
__global__ void __launch_bounds__(1024) k_finish2(const u64* __restrict__ cb,
                                                  const unsigned* __restrict__ cur,
                                                  u64* __restrict__ state) {
  __shared__ unsigned lh[4096];
  __shared__ unsigned ssum[1024];
  __shared__ u64 cand[FCAP];
  __shared__ unsigned ccnt;
  __shared__ u64 spref;
  __shared__ unsigned skrem;
  int t = threadIdx.x;
  unsigned cnt = cur[0];
  if (t == 0) { spref = state[0]; skrem = (unsigned)state[1]; ccnt = 0u; }
  for (int i = t; i < 4096; i += 1024) lh[i] = 0u;
  __syncthreads();

  // ---- round 0: bits 40-51, streaming global (all cb entries match the
  // 52-bit prefix by construction -> no check needed) ----
  for (unsigned j = t; j < cnt; j += 1024)
    atomicAdd(&lh[(unsigned)((cb[j] >> 40) & 4095ull)], 1u);
  __syncthreads();
  {
    unsigned loc[4]; unsigned tot = 0;
    #pragma unroll
    for (int i = 0; i < 4; i++) { loc[i] = lh[t * 4 + i]; tot += loc[i]; }
    unsigned krem = skrem;
    ssum[t] = tot; __syncthreads();
    for (int off = 1; off < 1024; off <<= 1) {
      unsigned x = (t >= off) ? ssum[t - off] : 0u;
      __syncthreads();
      ssum[t] += x;
      __syncthreads();
    }
    unsigned incl = ssum[t], excl = incl - tot;
    __syncthreads();
    if (incl >= krem && excl < krem) {
      unsigned run = excl;
      #pragma unroll
      for (int i = 0; i < 4; i++) {
        if (krem <= run + loc[i]) {
          spref |= ((u64)(t * 4 + i)) << 40;
          skrem = krem - run;
          break;
        }
        run += loc[i];
      }
    }
    __syncthreads();
  }

  // ---- compact survivors of the 24-bit prefix into LDS ----
  u64 pref24 = spref;
  for (unsigned j = t; j < cnt; j += 1024) {
    u64 k = cb[j];
    if ((k >> 40) == (pref24 >> 40)) {
      unsigned p = atomicAdd(&ccnt, 1u);
      if (p < (unsigned)FCAP) cand[p] = k;
    }
  }
  __syncthreads();
  bool lds_ok = (ccnt <= (unsigned)FCAP);
  unsigned n2 = lds_ok ? ccnt : cnt;

  // ---- rounds 1-4 on the small set (LDS if it fit, global fallback) ----
  for (int r = 1; r < 5; r++) {
    int shift = (r < 4) ? (40 - 12 * r) : 0;
    int width = (r < 4) ? 12 : 4;
    int nbins = 1 << width;
    int check = shift + width;
    for (int i = t; i < nbins; i += 1024) lh[i] = 0u;
    __syncthreads();
    u64 pref = spref;
    for (unsigned j = t; j < n2; j += 1024) {
      u64 k = lds_ok ? cand[j] : cb[j];
      if (((k ^ pref) >> check) == 0ull)
        atomicAdd(&lh[(unsigned)((k >> shift) & (u64)(nbins - 1))], 1u);
    }
    __syncthreads();
    int per = (nbins + 1023) / 1024;        // 4 or 1
    unsigned loc[4]; unsigned tot = 0;
    for (int i = 0; i < per; i++) {
      int b = t * per + i;
      loc[i] = (b < nbins) ? lh[b] : 0u;
      tot += loc[i];
    }
    ssum[t] = tot; __syncthreads();
    for (int off = 1; off < 1024; off <<= 1) {
      unsigned x = (t >= off) ? ssum[t - off] : 0u;
      __syncthreads();
      ssum[t] += x;
      __syncthreads();
    }
    unsigned incl = ssum[t], excl = incl - tot;
    unsigned krem = skrem;
    __syncthreads();
    if (incl >= krem && excl < krem) {
      unsigned run = excl;
      for (int i = 0; i < per; i++) {
        if (krem <= run + loc[i]) {
          spref |= ((u64)(t * per + i)) << shift;
          skrem = krem - run;
          break;
        }
        run += loc[i];
      }
    }
    __syncthreads();
  }
  if (t == 0) state[0] = spref;   // exact K-th smallest key
}

// ---------------- propagate, MLP-restructured like k_cos ----------------

__global__ void k_prop(const unsigned* __restrict__ rowptr, const uint2* __restrict__ csr,
                       const u64* __restrict__ key, const u64* __restrict__ state,
                       const float* __restrict__ hn, const float* __restrict__ nrm,
                       float* __restrict__ hout) {
  int t = threadIdx.x;
  int lane = t & 31;
  int sl = lane >> 2, ds = lane & 3;
  int n = blockIdx.x * 8 + (t >> 5);
  u64 X = state[0];                         // cut iff key <= X
  unsigned j0 = rowptr[n], j1 = rowptr[n + 1];
  double acc[8];
  #pragma unroll
  for (int i = 0; i < 8; i++) acc[i] = 0.0;
  for (unsigned base = j0; base < j1; base += 8) {
    unsigned j = base + sl;
    bool val = (j < j1);
    uint2 c = val ? csr[j] : make_uint2(0u, 0u);
    u64 k = val ? key[j] : 0ull;
    bool keep = val && (k > X);
    const float4* arow = (const float4*)(hn + (size_t)c.x * DI + ds * 8);
    float4 a0 = arow[0], a1 = arow[1];      // two independent gathers
    if (keep) {
      acc[0] += (double)a0.x; acc[1] += (double)a0.y;
      acc[2] += (double)a0.z; acc[3] += (double)a0.w;
      acc[4] += (double)a1.x; acc[5] += (double)a1.y;
      acc[6] += (double)a1.z; acc[7] += (double)a1.w;
    }
  }
  #pragma unroll
  for (int m = 4; m <= 16; m <<= 1) {
    #pragma unroll
    for (int i = 0; i < 8; i++) acc[i] += __shfl_xor(acc[i], m, 32);
  }
  if (sl == 0) {                            // lanes 0..3 hold dims ds*8..ds*8+7
    float nv = nrm[n];
    float4 o0, o1;
    o0.x = (float)acc[0] * nv; o0.y = (float)acc[1] * nv;
    o0.z = (float)acc[2] * nv; o0.w = (float)acc[3] * nv;
    o1.x = (float)acc[4] * nv; o1.y = (float)acc[5] * nv;
    o1.z = (float)acc[6] * nv; o1.w = (float)acc[7] * nv;
    float4* orow = (float4*)(hout + (size_t)n * DI + ds * 8);
    orow[0] = o0; orow[1] = o1;
  }
}

// ---------------- final FC: out = h @ W^T ----------------

__global__ void k_fc(const float* __restrict__ h, const float* __restrict__ W,
                     float* __restrict__ out) {
  __shared__ float Wt[DI * 65];   // Wt[d][o], padded stride 65
  __shared__ float hs[4 * DI];
  int t = threadIdx.x;
  #pragma unroll
  for (int i = 0; i < 8; i++) {
    int idx = t + i * 256;                 // idx = o*32 + d
    Wt[(idx & 31) * 65 + (idx >> 5)] = W[idx];
  }
  int n0 = blockIdx.x * 4;
  if (t < 128) hs[t] = h[n0 * DI + t];
  __syncthreads();
  int o = t & 63, nl = t >> 6;
  float acc = 0.f;
  #pragma unroll
  for (int d = 0; d < DI; d++) acc += hs[nl * DI + d] * Wt[d * 65 + o];
  out[(n0 + nl) * DO + o] = acc;
}

// ---------------- launch ----------------

extern "C" void kernel_launch(void* const* d_in, const int* in_sizes, int n_in,
                              void* d_out, int out_size, void* d_ws, size_t ws_size,
                              hipStream_t stream) {
  const float* feat = (const float*)d_in[0];
  const int*   src  = (const int*)d_in[1];
  const int*   dst  = (const int*)d_in[2];
  const float* W    = (const float*)d_in[3];
  float*       out  = (float*)d_out;

  // workspace layout (~80 MB), all u64 pointers 8B-aligned
  float* bufA = (float*)d_ws;                       // NN*DI f32
  float* bufB = bufA + (size_t)NN * DI;
  float* bufC = bufB + (size_t)NN * DI;
  u64*   key  = (u64*)(bufC + (size_t)NN * DI);     // NE u64
  u64*   cbuf2 = key + NE;                          // NE u64 (aliased: binned, ghist)
  u64*   binned = cbuf2;                            // dead before cbuf1 is used
  unsigned* ghist = (unsigned*)cbuf2;               // HB*4096 u32 = 4MB
  float*    nrm     = (float*)(cbuf2 + NE);
  unsigned* degi    = (unsigned*)(nrm + NN);
  unsigned* rowptr  = degi + NN;                    // NN+2 (pad keeps 8B alignment)
  unsigned* fill    = rowptr + NN + 2;              // (unused, layout stability)
  unsigned* bsum    = fill + NN;                    // 128
  unsigned* hist    = bsum + 128;                   // 4096
  unsigned* cur     = hist + 4096;                  // 4: cnt1, spare, done, pad
  u64*      state   = (u64*)(cur + 4);              // 2
  uint2*    csr     = (uint2*)(state + 2);          // NE uint2
  unsigned* bstart  = (unsigned*)(csr + NE);        // NB+1 (pad to 100)
  unsigned* bcur    = bstart + 100;                 // 128
  unsigned* bpart   = bcur + 128;                   // HBH*128 = 256KB

  // ---- binned CSR build (edges are hop-invariant) ----
  k_bhist<<<HBH, 256, 0, stream>>>(dst, bpart);
  k_bscan2<<<1, 128, 0, stream>>>(bpart, bstart, bcur);
  k_bin<<<(NE + CH - 1) / CH, 256, 0, stream>>>(src, dst, bcur, binned);
  k_bucket_deg<<<NB, 256, 0, stream>>>(binned, bstart, degi);
  int nb = (NN + 1023) / 1024;   // 98
  k_psum_a<<<nb, 1024, 0, stream>>>(degi, bsum);
  k_psum_b<<<1, 1, 0, stream>>>(bsum, nb, rowptr);
  k_psum_c<<<nb, 1024, 0, stream>>>(degi, bsum, rowptr, nrm);
  size_t scatter_lds = 1024 * sizeof(unsigned) + (size_t)SCAP * sizeof(u64);  // ~156KB
  k_bucket_scatter<<<NB, 256, scatter_lds, stream>>>(binned, bstart, rowptr, csr);

  // hop 0: nh=A, hn=B, out=A, cbuf1=C   |   hop 1: nh=C, hn=B, out=C, cbuf1=A
  const float* hin = feat;
  for (int hop = 0; hop < 2; hop++) {
    float* nh = (hop == 0) ? bufA : bufC;
    float* hn = bufB;
    float* ho = (hop == 0) ? bufA : bufC;
    u64* cbuf1 = (u64*)((hop == 0) ? bufC : bufA);  // free this hop

    k_rownorm<<<NN / 8, 256, 0, stream>>>(hin, nrm, nh, hn);
    k_cos<<<NN / 8, 256, 0, stream>>>(rowptr, csr, nh, key);

    k_hist_big<<<HB, 256, 0, stream>>>(key, ghist, state, cur);      // + init
    k_hist_reduce_sel<<<16, 256, 0, stream>>>(ghist, hist, state, cur);
    k_compact<<<512, 256, 0, stream>>>(key, state, cbuf1, cur + 0);
    k_finish2<<<1, 1024, 0, stream>>>(cbuf1, cur, state);

    k_prop<<<NN / 8, 256, 0, stream>>>(rowptr, csr, key, state, hn, nrm, ho);
    hin = ho;
  }
  k_fc<<<NN / 4, 256, 0, stream>>>(hin, W, out);
}